// Round 1
// baseline (11508.673 us; speedup 1.0000x reference)
//
#include <hip/hip_runtime.h>
#include <math.h>

#define Bsz 2
#define Tsz 2048
#define Esz 1024
#define Hsz 16
#define Vsz 32000
#define Dsz 64
#define BT  (Bsz*Tsz)   // 4096

// ---------------- embedding: x[bt,e] = tok_table[tokens[bt],e] + pos_emb[t,e]
__global__ __launch_bounds__(256) void embed_kernel(const int* __restrict__ tokens,
                                                    const float* __restrict__ tok_table,
                                                    const float* __restrict__ pos_emb,
                                                    float* __restrict__ x) {
    int idx = blockIdx.x * 256 + threadIdx.x;       // over BT*E = 4M
    int e  = idx & (Esz - 1);
    int bt = idx >> 10;
    int t  = bt & (Tsz - 1);
    x[idx] = tok_table[(size_t)tokens[bt] * Esz + e] + pos_emb[t * Esz + e];
}

// ---------------- GEMM: C[m,n] = sum_k A[m,k]*W[n,k] + bias[n]
// MODE 0: C row-major [M,N].  MODE 1: scatter to q/k/v layout [B,H,T,D] with n=h*64+d, m=b*T+t.
template <int MODE>
__global__ __launch_bounds__(256) void gemm_bias(const float* __restrict__ A,
                                                 const float* __restrict__ W,
                                                 const float* __restrict__ bias,
                                                 float* __restrict__ C,
                                                 int M, int N, int K) {
    constexpr int BM = 64, BN = 64, BK = 16;
    __shared__ float As[BK][BM + 1];
    __shared__ float Ws[BK][BN + 1];
    const int tid = threadIdx.x;
    const int tx = tid & 15;          // n-quad
    const int ty = tid >> 4;          // m-quad
    const int row0 = blockIdx.y * BM;
    const int col0 = blockIdx.x * BN;
    const int lr = tid >> 2;          // 0..63 tile row
    const int lc = (tid & 3) * 4;     // 0,4,8,12 tile k
    float acc[4][4] = {};
    for (int k0 = 0; k0 < K; k0 += BK) {
        float4 av = *(const float4*)&A[(size_t)(row0 + lr) * K + k0 + lc];
        float4 wv = *(const float4*)&W[(size_t)(col0 + lr) * K + k0 + lc];
        As[lc + 0][lr] = av.x; As[lc + 1][lr] = av.y; As[lc + 2][lr] = av.z; As[lc + 3][lr] = av.w;
        Ws[lc + 0][lr] = wv.x; Ws[lc + 1][lr] = wv.y; Ws[lc + 2][lr] = wv.z; Ws[lc + 3][lr] = wv.w;
        __syncthreads();
#pragma unroll
        for (int kk = 0; kk < BK; ++kk) {
            float a0 = As[kk][ty * 4 + 0], a1 = As[kk][ty * 4 + 1];
            float a2 = As[kk][ty * 4 + 2], a3 = As[kk][ty * 4 + 3];
            float b0 = Ws[kk][tx * 4 + 0], b1 = Ws[kk][tx * 4 + 1];
            float b2 = Ws[kk][tx * 4 + 2], b3 = Ws[kk][tx * 4 + 3];
            acc[0][0] += a0 * b0; acc[0][1] += a0 * b1; acc[0][2] += a0 * b2; acc[0][3] += a0 * b3;
            acc[1][0] += a1 * b0; acc[1][1] += a1 * b1; acc[1][2] += a1 * b2; acc[1][3] += a1 * b3;
            acc[2][0] += a2 * b0; acc[2][1] += a2 * b1; acc[2][2] += a2 * b2; acc[2][3] += a2 * b3;
            acc[3][0] += a3 * b0; acc[3][1] += a3 * b1; acc[3][2] += a3 * b2; acc[3][3] += a3 * b3;
        }
        __syncthreads();
    }
#pragma unroll
    for (int i = 0; i < 4; ++i)
#pragma unroll
        for (int j = 0; j < 4; ++j) {
            int m = row0 + ty * 4 + i;
            int n = col0 + tx * 4 + j;
            float val = acc[i][j] + bias[n];
            if (MODE == 0) {
                C[(size_t)m * N + n] = val;
            } else {
                int b = m >> 11, t = m & (Tsz - 1);
                int h = n >> 6, d = n & 63;
                C[((((size_t)b * Hsz + h) * Tsz + t) << 6) + d] = val;
            }
        }
}

// ---------------- attention: one block per (b,h,t) row; scores in LDS; two-pass softmax
__global__ __launch_bounds__(256) void attn_kernel(const float* __restrict__ q,
                                                   const float* __restrict__ k,
                                                   const float* __restrict__ v,
                                                   float* __restrict__ o) {
    __shared__ float sc[Tsz];
    __shared__ float qs[Dsz];
    __shared__ float red[256];
    __shared__ float oacc[256];

    const int bi = blockIdx.x;            // (b*H+h)*T + t
    const int t  = bi & (Tsz - 1);
    const int bh = bi >> 11;              // b*H + h
    const int h  = bh & (Hsz - 1);
    const int b  = bh >> 4;
    const int tid = threadIdx.x;
    const int lane = tid & 63;
    const int wv = tid >> 6;              // 4 waves

    if (tid < Dsz) qs[tid] = q[((size_t)bh * Tsz + t) * Dsz + tid];
    __syncthreads();

    const int nS = t + 1;
    // phase 1: raw scores with faithful mask quirk
    for (int s = wv; s < nS; s += 4) {
        float p = qs[lane] * k[((size_t)bh * Tsz + s) * Dsz + lane];
#pragma unroll
        for (int off = 32; off > 0; off >>= 1) p += __shfl_down(p, off, 64);
        if (lane == 0) {
            if (p == 0.0f) p = -INFINITY;   // reference: w==0 -> -inf (covers causal-zeroed too)
            sc[s] = p;
        }
    }
    __syncthreads();

    // max
    float mx = -INFINITY;
    for (int s = tid; s < nS; s += 256) mx = fmaxf(mx, sc[s]);
    red[tid] = mx; __syncthreads();
    for (int st = 128; st > 0; st >>= 1) { if (tid < st) red[tid] = fmaxf(red[tid], red[tid + st]); __syncthreads(); }
    mx = red[0]; __syncthreads();

    // exp + sum
    float sm = 0.0f;
    for (int s = tid; s < nS; s += 256) { float e = expf(sc[s] - mx); sc[s] = e; sm += e; }
    red[tid] = sm; __syncthreads();
    for (int st = 128; st > 0; st >>= 1) { if (tid < st) red[tid] += red[tid + st]; __syncthreads(); }
    const float scale = 1.0f / (red[0] * 8.0f);   // softmax denom * sqrt(D)
    __syncthreads();

    // phase 2: o[d] = scale * sum_s sc[s]*v[s,d]
    const int d = tid & 63, part = tid >> 6;
    float acc = 0.0f;
    for (int s = part; s < nS; s += 4) acc += sc[s] * v[((size_t)bh * Tsz + s) * Dsz + d];
    oacc[tid] = acc; __syncthreads();
    if (tid < 64) {
        float tot = (oacc[tid] + oacc[64 + tid]) + (oacc[128 + tid] + oacc[192 + tid]);
        o[((size_t)(b * Tsz + t)) * Esz + h * Dsz + d] = tot * scale;
    }
}

// ---------------- per-row NLL: rl[row] = lse(logits[row,:]) - logits[row,target]
__global__ __launch_bounds__(256) void rowloss_kernel(const float* __restrict__ logits,
                                                      const int* __restrict__ targets,
                                                      float* __restrict__ rl) {
    const int row = blockIdx.x;
    const float* lr = logits + (size_t)row * Vsz;
    __shared__ float red[256];
    const int tid = threadIdx.x;
    float m = -INFINITY;
    for (int i = tid; i < Vsz; i += 256) m = fmaxf(m, lr[i]);
    red[tid] = m; __syncthreads();
    for (int st = 128; st > 0; st >>= 1) { if (tid < st) red[tid] = fmaxf(red[tid], red[tid + st]); __syncthreads(); }
    m = red[0]; __syncthreads();
    float s = 0.0f;
    for (int i = tid; i < Vsz; i += 256) s += expf(lr[i] - m);
    red[tid] = s; __syncthreads();
    for (int st = 128; st > 0; st >>= 1) { if (tid < st) red[tid] += red[tid + st]; __syncthreads(); }
    if (tid == 0) rl[row] = (m + logf(red[0])) - lr[targets[row]];
}

__global__ __launch_bounds__(256) void loss_reduce_kernel(const float* __restrict__ rl,
                                                          float* __restrict__ out_loss) {
    __shared__ float red[256];
    const int tid = threadIdx.x;
    float s = 0.0f;
    for (int i = tid; i < BT; i += 256) s += rl[i];
    red[tid] = s; __syncthreads();
    for (int st = 128; st > 0; st >>= 1) { if (tid < st) red[tid] += red[tid + st]; __syncthreads(); }
    if (tid == 0) out_loss[0] = red[0] / (float)BT;
}

extern "C" void kernel_launch(void* const* d_in, const int* in_sizes, int n_in,
                              void* d_out, int out_size, void* d_ws, size_t ws_size,
                              hipStream_t stream) {
    const int*   tokens    = (const int*)d_in[0];
    const int*   targets   = (const int*)d_in[1];
    const float* tok_table = (const float*)d_in[2];
    const float* pos_emb   = (const float*)d_in[3];
    const float* Wq        = (const float*)d_in[4];
    const float* bq        = (const float*)d_in[5];
    const float* Wk        = (const float*)d_in[6];
    const float* bk        = (const float*)d_in[7];
    const float* Wv        = (const float*)d_in[8];
    const float* bv        = (const float*)d_in[9];
    const float* Wo        = (const float*)d_in[10];
    const float* bo        = (const float*)d_in[11];

    float* out    = (float*)d_out;
    float* logits = out;                              // [BT, V]
    float* loss   = out + (size_t)BT * Vsz;           // scalar

    float* ws = (float*)d_ws;
    const size_t NXE = (size_t)BT * Esz;              // 4M
    float* x  = ws;
    float* q  = x + NXE;
    float* k  = q + NXE;
    float* v  = k + NXE;
    float* o  = v + NXE;
    float* rl = o + NXE;

    // 1) embedding
    embed_kernel<<<(BT * Esz) / 256, 256, 0, stream>>>(tokens, tok_table, pos_emb, x);

    // 2) QKV projections -> [B,H,T,D]
    dim3 gqkv(Esz / 64, BT / 64);
    gemm_bias<1><<<gqkv, 256, 0, stream>>>(x, Wq, bq, q, BT, Esz, Esz);
    gemm_bias<1><<<gqkv, 256, 0, stream>>>(x, Wk, bk, k, BT, Esz, Esz);
    gemm_bias<1><<<gqkv, 256, 0, stream>>>(x, Wv, bv, v, BT, Esz, Esz);

    // 3) attention (one block per (b,h,t))
    attn_kernel<<<Bsz * Hsz * Tsz, 256, 0, stream>>>(q, k, v, o);

    // 4) logits GEMM [BT,V]
    dim3 glog(Vsz / 64, BT / 64);
    gemm_bias<0><<<glog, 256, 0, stream>>>(o, Wo, bo, logits, BT, Vsz, Esz);

    // 5) loss
    rowloss_kernel<<<BT, 256, 0, stream>>>(logits, targets, rl);
    loss_reduce_kernel<<<1, 256, 0, stream>>>(rl, loss);
}